// Round 1
// baseline (82.847 us; speedup 1.0000x reference)
//
#include <hip/hip_runtime.h>
#include <float.h>

// ChamferLoss: B=4 batches, N=16384 src points, M=4096 target verts, fp32.
// loss[b] = (1/N) * sum_n min_m max(||p_bn - v_bm||^2, 0)
//
// Strategy:
//   d2 = p2 + v2 - 2*dot(p,v).  p2 is constant per point -> fold out of the
//   inner loop; verts pre-transformed to w = {-2x,-2y,-2z, v2} so the inner
//   body is d = fma(wx,px, fma(wy,py, fma(wz,pz, v2))) then min: 4 VALU/pair.
//   max(.,0) per-element before the min is equivalent to clamping after the
//   min (min of clamped == clamp of min), so we clamp once per point at the end.

constexpr int B = 4, N = 16384, M = 4096;
constexpr int C   = 16;        // vert chunks per batch (M split across blocks)
constexpr int VC  = M / C;     // 256 verts per chunk
constexpr int P   = 8;         // points per thread (amortize LDS read over 32 VALU)
constexpr int TPB = 256;
constexpr int PPB = TPB * P;   // 2048 points per block
constexpr int PB  = (B * N) / PPB; // 32 point-blocks

// grid = PB * C = 512 blocks; block (pb, c) computes, for its 2048 points,
// the min over verts [c*VC, (c+1)*VC) of the chunk-relative distance, and
// stores (min + p2) into partial[point*C + c].
__global__ __launch_bounds__(TPB) void chamfer_main(
    const float* __restrict__ src, const float* __restrict__ tv,
    float* __restrict__ partial, float* __restrict__ out)
{
    __shared__ float4 lv[VC];
    const int blk = blockIdx.x;
    const int c   = blk & (C - 1);
    const int pb  = blk >> 4;          // log2(C) = 4
    const int b   = pb >> 3;           // 8 point-blocks per batch (16384/2048)

    // Zero the output; stream order guarantees this completes before the
    // reduce kernel's atomicAdds. (d_out is poisoned before every launch.)
    if (blk == 0 && threadIdx.x < B) out[threadIdx.x] = 0.0f;

    // Stage this chunk's verts into LDS, pre-transformed to {-2x,-2y,-2z,v2}.
    const float* vsrc = tv + ((size_t)b * M + (size_t)c * VC) * 3;
    for (int i = threadIdx.x; i < VC; i += TPB) {
        float x = vsrc[3 * i + 0];
        float y = vsrc[3 * i + 1];
        float z = vsrc[3 * i + 2];
        lv[i] = make_float4(-2.0f * x, -2.0f * y, -2.0f * z,
                            fmaf(x, x, fmaf(y, y, z * z)));
    }
    __syncthreads();

    // Load this thread's 8 consecutive points (24 contiguous floats).
    const int p0 = pb * PPB + threadIdx.x * P;
    const float* ps = src + (size_t)p0 * 3;
    float px[P], py[P], pz[P], mn[P];
#pragma unroll
    for (int p = 0; p < P; ++p) {
        px[p] = ps[3 * p + 0];
        py[p] = ps[3 * p + 1];
        pz[p] = ps[3 * p + 2];
        mn[p] = FLT_MAX;
    }

    // Inner loop: 1 broadcast ds_read_b128 + 8 * (3 FMA + 1 min).
#pragma unroll 4
    for (int j = 0; j < VC; ++j) {
        float4 v = lv[j];
#pragma unroll
        for (int p = 0; p < P; ++p) {
            float d = fmaf(v.x, px[p], fmaf(v.y, py[p], fmaf(v.z, pz[p], v.w)));
            mn[p] = fminf(mn[p], d);
        }
    }

#pragma unroll
    for (int p = 0; p < P; ++p) {
        float p2 = fmaf(px[p], px[p], fmaf(py[p], py[p], pz[p] * pz[p]));
        partial[(size_t)(p0 + p) * C + c] = mn[p] + p2;
    }
}

// grid = 64 blocks x 256 threads; block g: batch b = g/16, a 1024-point
// segment. Min over the 16 chunk-partials per point, clamp to 0, block-sum,
// one atomicAdd per block into out[b].
__global__ __launch_bounds__(256) void chamfer_reduce(
    const float* __restrict__ partial, float* __restrict__ out)
{
    const int g = blockIdx.x;
    const int b = g >> 4;
    const int seg = g & 15;
    const int pbase = b * N + seg * 1024;

    float sum = 0.0f;
#pragma unroll
    for (int k = 0; k < 4; ++k) {
        int p = pbase + k * 256 + threadIdx.x;
        const float4* q = (const float4*)(partial + (size_t)p * C);
        float4 a = q[0], d = q[1], e = q[2], f = q[3];
        float m = fminf(
            fminf(fminf(fminf(a.x, a.y), fminf(a.z, a.w)),
                  fminf(fminf(d.x, d.y), fminf(d.z, d.w))),
            fminf(fminf(fminf(e.x, e.y), fminf(e.z, e.w)),
                  fminf(fminf(f.x, f.y), fminf(f.z, f.w))));
        sum += fmaxf(m, 0.0f);
    }

    // wave reduce (64 lanes), then cross-wave via LDS
    for (int off = 32; off > 0; off >>= 1)
        sum += __shfl_down(sum, off, 64);
    __shared__ float acc[4];
    if ((threadIdx.x & 63) == 0) acc[threadIdx.x >> 6] = sum;
    __syncthreads();
    if (threadIdx.x == 0) {
        float s = acc[0] + acc[1] + acc[2] + acc[3];
        atomicAdd(&out[b], s * (1.0f / N));
    }
}

extern "C" void kernel_launch(void* const* d_in, const int* in_sizes, int n_in,
                              void* d_out, int out_size, void* d_ws, size_t ws_size,
                              hipStream_t stream) {
    const float* src = (const float*)d_in[0];  // (B, N, 3) fp32
    const float* tv  = (const float*)d_in[1];  // (B, M, 3) fp32
    float* out = (float*)d_out;                // (B,) fp32
    float* partial = (float*)d_ws;             // B*N*C floats = 4 MB scratch

    chamfer_main<<<PB * C, TPB, 0, stream>>>(src, tv, partial, out);
    chamfer_reduce<<<64, 256, 0, stream>>>(partial, out);
}

// Round 2
// 81.578 us; speedup vs baseline: 1.0156x; 1.0156x over previous
//
#include <hip/hip_runtime.h>
#include <float.h>

// ChamferLoss: B=4, N=16384 src points, M=4096 target verts, fp32.
// loss[b] = (1/N) * sum_n min_m max(||p_bn - v_bm||^2, 0)
//
// d2 = p2 + v2 - 2*dot(p,v).  p2 folded out of inner loop (constant per
// point, added after the min; clamp commutes with min). Verts pre-transformed
// to {-2x,-2y,-2z,v2} -> inner body = 3 FMA + 1 min per pair (4 VALU lane-ops).
// VALU floor: 4*4*16384*4096 lane-ops / 78.6 T/s = 13.7 us.

constexpr int B = 4, N = 16384, M = 4096;
constexpr int BN  = B * N;     // 65536 points
constexpr int C   = 32;        // vert chunks per batch
constexpr int VC  = M / C;     // 128 verts per chunk
constexpr int P   = 8;         // points per thread
constexpr int TPB = 256;
constexpr int PPB = TPB * P;   // 2048 points per block
constexpr int PB  = BN / PPB;  // 32 point-blocks
// grid = PB*C = 1024 blocks -> 4 blocks/CU -> 4 waves/SIMD

__global__ __launch_bounds__(TPB) void chamfer_main(
    const float* __restrict__ src, const float* __restrict__ tv,
    float* __restrict__ partial, float* __restrict__ out)
{
    __shared__ float4 lv[VC];
    const int blk = blockIdx.x;
    const int c   = blk & (C - 1);
    const int pb  = blk >> 5;          // log2(C) = 5
    const int b   = pb >> 3;           // 8 point-blocks per batch

    // Zero output (d_out is poisoned before every launch); stream order
    // guarantees completion before chamfer_reduce's atomicAdds.
    if (blk == 0 && threadIdx.x < B) out[threadIdx.x] = 0.0f;

    // Stage chunk verts into LDS, pre-transformed to {-2x,-2y,-2z,v2}.
    const float* vsrc = tv + ((size_t)b * M + (size_t)c * VC) * 3;
    for (int i = threadIdx.x; i < VC; i += TPB) {
        float x = vsrc[3 * i + 0];
        float y = vsrc[3 * i + 1];
        float z = vsrc[3 * i + 2];
        lv[i] = make_float4(-2.0f * x, -2.0f * y, -2.0f * z,
                            fmaf(x, x, fmaf(y, y, z * z)));
    }
    __syncthreads();

    // Load this thread's 8 consecutive points (96 B, 16B-aligned) as 6 float4.
    const int p0 = pb * PPB + threadIdx.x * P;
    const float4* pv4 = (const float4*)(src + (size_t)p0 * 3);
    float4 q0 = pv4[0], q1 = pv4[1], q2 = pv4[2],
           q3 = pv4[3], q4 = pv4[4], q5 = pv4[5];
    float px[P], py[P], pz[P], mn[P];
    px[0]=q0.x; py[0]=q0.y; pz[0]=q0.z;
    px[1]=q0.w; py[1]=q1.x; pz[1]=q1.y;
    px[2]=q1.z; py[2]=q1.w; pz[2]=q2.x;
    px[3]=q2.y; py[3]=q2.z; pz[3]=q2.w;
    px[4]=q3.x; py[4]=q3.y; pz[4]=q3.z;
    px[5]=q3.w; py[5]=q4.x; pz[5]=q4.y;
    px[6]=q4.z; py[6]=q4.w; pz[6]=q5.x;
    px[7]=q5.y; py[7]=q5.z; pz[7]=q5.w;
#pragma unroll
    for (int p = 0; p < P; ++p) mn[p] = FLT_MAX;

    // Inner loop: unroll 8 -> 8 outstanding broadcast ds_read_b128 at body
    // head, then 256 VALU instrs (512 issue cyc) to cover LDS latency.
#pragma unroll 8
    for (int j = 0; j < VC; ++j) {
        float4 v = lv[j];
#pragma unroll
        for (int p = 0; p < P; ++p) {
            float d = fmaf(v.x, px[p], fmaf(v.y, py[p], fmaf(v.z, pz[p], v.w)));
            mn[p] = fminf(mn[p], d);
        }
    }

    // partial layout: [chunk][point] -> this thread's 8 results contiguous.
    float o[P];
#pragma unroll
    for (int p = 0; p < P; ++p) {
        float p2 = fmaf(px[p], px[p], fmaf(py[p], py[p], pz[p] * pz[p]));
        o[p] = mn[p] + p2;
    }
    float4* dst = (float4*)(partial + (size_t)c * BN + p0);
    dst[0] = make_float4(o[0], o[1], o[2], o[3]);
    dst[1] = make_float4(o[4], o[5], o[6], o[7]);
}

// grid = 256 blocks x 256 threads; thread -> one point. Min over C chunk
// partials (lane-coalesced reads), clamp, block-sum, one atomicAdd per block.
__global__ __launch_bounds__(256) void chamfer_reduce(
    const float* __restrict__ partial, float* __restrict__ out)
{
    const int p = blockIdx.x * 256 + threadIdx.x;
    const int b = blockIdx.x >> 6;     // 64 blocks per batch (16384/256)

    float m = FLT_MAX;
#pragma unroll
    for (int c = 0; c < C; ++c) m = fminf(m, partial[(size_t)c * BN + p]);
    float sum = fmaxf(m, 0.0f);

    // wave reduce (64 lanes), then cross-wave via LDS
    for (int off = 32; off > 0; off >>= 1)
        sum += __shfl_down(sum, off, 64);
    __shared__ float acc[4];
    if ((threadIdx.x & 63) == 0) acc[threadIdx.x >> 6] = sum;
    __syncthreads();
    if (threadIdx.x == 0) {
        float s = acc[0] + acc[1] + acc[2] + acc[3];
        atomicAdd(&out[b], s * (1.0f / N));
    }
}

extern "C" void kernel_launch(void* const* d_in, const int* in_sizes, int n_in,
                              void* d_out, int out_size, void* d_ws, size_t ws_size,
                              hipStream_t stream) {
    const float* src = (const float*)d_in[0];  // (B, N, 3) fp32
    const float* tv  = (const float*)d_in[1];  // (B, M, 3) fp32
    float* out = (float*)d_out;                // (B,) fp32
    float* partial = (float*)d_ws;             // C*BN floats = 8 MB scratch

    chamfer_main<<<PB * C, TPB, 0, stream>>>(src, tv, partial, out);
    chamfer_reduce<<<256, 256, 0, stream>>>(partial, out);
}